// Round 4
// baseline (193.644 us; speedup 1.0000x reference)
//
#include <hip/hip_runtime.h>

// STFT: x[16, 262144] fp32, Hann 2048, hop 512, reflect pad 1024.
// Output: real[16,1025,513] ++ imag[16,1025,513], fp32.
//
// Round 4: single fused kernel.
//  - 8 consecutive frames per block = 4 packed complex 2048-FFTs (z = even + i*odd),
//    512 threads (128 per sub-FFT). LDS 4 x 2112 float2 = 66 KB -> 2 blocks/CU.
//  - Epilogue writes out[b][k][f0..f0+7] directly: 32 B contiguous per lane per
//    half -> <=2x write amplification, NO staging buffer, NO transpose kernel
//    (round 3 spent ~95 us on the 201 MB staging round-trip).
//  - Twiddles: global per-stage table tw[half+pos] (16 KB, L1-resident,
//    stride-1 coalesced) -- keeps LDS at 66 KB for 2 blocks/CU.

#define N_FFT   2048
#define LOG2N   11
#define HOP     512
#define PADL    1024
#define NBINS   1025
#define NFRAMES 513
#define NBATCH  16
#define TLEN    262144

#define FPB     8      // frames per block
#define NSUB    4      // packed complex FFTs per block
#define TPB     512    // threads per block
#define TPS     128    // threads per sub-FFT
#define NGROUPS ((NFRAMES + FPB - 1) / FPB)   // 65

#define HALF_OUT ((size_t)NBATCH * NBINS * NFRAMES)   // 8,413,200 floats
#define TW_COUNT 2048

__device__ __forceinline__ int pidx(int a) { return a + (a >> 5); }

__device__ __forceinline__ int refl(int j) {
    if (j < 0)          j = -j;
    else if (j >= TLEN) j = 2 * TLEN - 2 - j;   // valid for j < 2*TLEN-1 (holds here)
    return j;
}

// tw[half + pos] = exp(-i*pi*pos/half), half = 1,2,4,...,1024
__global__ __launch_bounds__(256) void twiddle_init(float2* __restrict__ tw) {
    int idx = blockIdx.x * 256 + threadIdx.x;
    if (idx >= TW_COUNT) return;
    int half = (idx == 0) ? 1 : (1 << (31 - __clz(idx)));
    int pos  = (idx == 0) ? 0 : idx - half;
    float s, c;
    sincosf(-3.14159265358979323f * (float)pos / (float)half, &s, &c);
    tw[idx] = make_float2(c, s);
}

template <bool TWG>
__global__ __launch_bounds__(TPB) void stft_fused(
    const float* __restrict__ x,
    const float* __restrict__ window,
    const float2* __restrict__ twg,
    float* __restrict__ out)
{
    __shared__ float2 z[NSUB][2112];   // pidx(2047)=2110

    const int g   = blockIdx.x;        // frame group, f0 = g*8
    const int b   = blockIdx.y;
    const int tid = threadIdx.x;
    const int c   = tid >> 7;          // sub-FFT 0..3
    const int t   = tid & (TPS - 1);   // 0..127
    const int f0  = g * FPB;
    const int fa  = f0 + 2 * c;        // even frame of this sub-FFT
    const int fb  = fa + 1;

    // ---- load two windowed frames into one complex sequence, bit-reversed ----
    const float* xb = x + (size_t)b * TLEN;
    const int basea = fa * HOP - PADL;
    const int baseb = fb * HOP - PADL;
    for (int n = t; n < N_FFT; n += TPS) {
        const float w  = window[n];
        const float va = xb[refl(basea + n)] * w;
        const float vb = xb[refl(baseb + n)] * w;
        const int r = (int)(__brev((unsigned)n) >> (32 - LOG2N));
        z[c][pidx(r)] = make_float2(va, vb);
    }
    __syncthreads();

    // ---- 11 radix-2 DIT stages ----
    for (int s = 1; s <= LOG2N; ++s) {
        const int half = 1 << (s - 1);
        for (int q = t; q < N_FFT / 2; q += TPS) {
            const int pos = q & (half - 1);
            const int i   = ((q >> (s - 1)) << s) + pos;
            const int j   = i + half;
            float2 w;
            if (TWG) {
                w = twg[half + pos];       // L1-resident, stride-1 across lanes
            } else {
                float ss, cc;
                sincosf(-3.14159265358979323f * (float)pos / (float)half, &ss, &cc);
                w = make_float2(cc, ss);
            }
            const float2 zj = z[c][pidx(j)];
            const float2 zi = z[c][pidx(i)];
            const float vr = fmaf(zj.x, w.x, -zj.y * w.y);
            const float vi = fmaf(zj.x, w.y,  zj.y * w.x);
            z[c][pidx(i)] = make_float2(zi.x + vr, zi.y + vi);
            z[c][pidx(j)] = make_float2(zi.x - vr, zi.y - vi);
        }
        __syncthreads();
    }

    // ---- unpack 8 real spectra + direct write out[b][k][f0..f0+7] ----
    // A = (Z[k]+conj(Z[N-k]))/2 (even frame), B = (Z[k]-conj(Z[N-k]))/(2i) (odd)
    float* __restrict__ outr = out;
    float* __restrict__ outi = out + HALF_OUT;
    const bool full = (f0 + FPB) <= NFRAMES;   // all 8 frames valid (g < 64)
    for (int k = tid; k < NBINS; k += TPB) {
        const int km = (N_FFT - k) & (N_FFT - 1);
        const size_t orow = ((size_t)b * NBINS + (size_t)k) * NFRAMES + (size_t)f0;
#pragma unroll
        for (int cc = 0; cc < NSUB; ++cc) {
            const float2 zk = z[cc][pidx(k)];
            const float2 zr = z[cc][pidx(km)];
            const float ar = 0.5f * (zk.x + zr.x);
            const float ai = 0.5f * (zk.y - zr.y);
            const float br = 0.5f * (zk.y + zr.y);
            const float bi = 0.5f * (zr.x - zk.x);
            if (full) {
                outr[orow + 2 * cc]     = ar;  outi[orow + 2 * cc]     = ai;
                outr[orow + 2 * cc + 1] = br;  outi[orow + 2 * cc + 1] = bi;
            } else {
                const int fae = f0 + 2 * cc;
                if (fae < NFRAMES)     { outr[orow + 2 * cc]     = ar;  outi[orow + 2 * cc]     = ai; }
                if (fae + 1 < NFRAMES) { outr[orow + 2 * cc + 1] = br;  outi[orow + 2 * cc + 1] = bi; }
            }
        }
    }
}

extern "C" void kernel_launch(void* const* d_in, const int* in_sizes, int n_in,
                              void* d_out, int out_size, void* d_ws, size_t ws_size,
                              hipStream_t stream) {
    const float* x      = (const float*)d_in[0];
    const float* window = (const float*)d_in[1];
    float* out          = (float*)d_out;

    dim3 grid(NGROUPS, NBATCH);   // 65 x 16 = 1040 blocks of 512

    if (ws_size >= TW_COUNT * sizeof(float2)) {
        float2* tw = (float2*)d_ws;
        twiddle_init<<<8, 256, 0, stream>>>(tw);
        stft_fused<true><<<grid, TPB, 0, stream>>>(x, window, tw, out);
    } else {
        stft_fused<false><<<grid, TPB, 0, stream>>>(x, window, nullptr, out);
    }
}

// Round 5
// 136.788 us; speedup vs baseline: 1.4157x; 1.4157x over previous
//
#include <hip/hip_runtime.h>

// STFT: x[16, 262144] fp32, Hann 2048, hop 512, reflect pad 1024.
// Output: real[16,1025,513] ++ imag[16,1025,513], fp32.
//
// Round 5: staged structure (R3) with a rebuilt FFT kernel.
//  - Radix-2^2: stage pairs fused into one LDS round trip -> 6 round trips /
//    barriers instead of 11 (R3's FFT was barrier/latency bound at 35% VALU).
//  - Twiddles read from the 16 KB global per-stage table (L2-resident,
//    stride-1 coalesced) -> LDS/block 33 KB -> 17 KB -> 8 blocks/CU (100% occ).
//  - Staging spec as interleaved float2 [b][f][k] (coalesced), then a 64x64
//    LDS-tile transpose: 256 B contiguous spans on both read and write
//    (write amp <= 1.25x vs the 3.2x that killed the round-4 direct write).

#define N_FFT   2048
#define LOG2N   11
#define HOP     512
#define PADL    1024
#define NBINS   1025
#define NFRAMES 513
#define NBATCH  16
#define TLEN    262144

#define HALF_OUT ((size_t)NBATCH * NBINS * NFRAMES)   // 8,413,200 floats per plane
#define TW_COUNT 2048                                  // per-stage tables, float2

__device__ __forceinline__ int pidx(int a) { return a + (a >> 5); }

__device__ __forceinline__ int refl(int j) {
    if (j < 0)          j = -j;
    else if (j >= TLEN) j = 2 * TLEN - 2 - j;
    return j;
}

__device__ __forceinline__ float2 cmul(float2 a, float2 w) {
    return make_float2(fmaf(a.x, w.x, -a.y * w.y), fmaf(a.x, w.y, a.y * w.x));
}
__device__ __forceinline__ float2 cadd(float2 a, float2 b) {
    return make_float2(a.x + b.x, a.y + b.y);
}
__device__ __forceinline__ float2 csub(float2 a, float2 b) {
    return make_float2(a.x - b.x, a.y - b.y);
}

// tw[half + pos] = exp(-i*pi*pos/half), half = 1,2,4,...,1024
__global__ __launch_bounds__(256) void twiddle_init(float2* __restrict__ tw) {
    int idx = blockIdx.x * 256 + threadIdx.x;
    if (idx >= TW_COUNT) return;
    int half = (idx == 0) ? 1 : (1 << (31 - __clz(idx)));
    int pos  = (idx == 0) ? 0 : idx - half;
    float s, c;
    sincosf(-3.14159265358979323f * (float)pos / (float)half, &s, &c);
    tw[idx] = make_float2(c, s);
}

// One block = one packed complex FFT of two consecutive frames (z = even + i*odd).
__global__ __launch_bounds__(256) void stft_fft_r4(
    const float* __restrict__ x,
    const float* __restrict__ window,
    const float2* __restrict__ twg,
    float2* __restrict__ spec2)       // [b][f][k] interleaved (re,im)
{
    __shared__ float2 z[2112];        // pidx(2047) = 2110, 16.9 KB -> 8 blocks/CU

    const int g   = blockIdx.x;       // frame pair
    const int b   = blockIdx.y;
    const int t   = threadIdx.x;      // 0..255
    const int fa  = 2 * g;
    const bool hasb = (fa + 1) < NFRAMES;
    const int fb  = fa + 1;           // phantom frame 513 still reads valid data

    // ---- load two windowed frames, bit-reversed, into LDS ----
    const float* xb = x + (size_t)b * TLEN;
    const int basea = fa * HOP - PADL;
    const int baseb = fb * HOP - PADL;
    for (int n = t; n < N_FFT; n += 256) {
        const float w  = window[n];
        const float va = xb[refl(basea + n)] * w;
        const float vb = xb[refl(baseb + n)] * w;
        const int r = (int)(__brev((unsigned)n) >> (32 - LOG2N));
        z[pidx(r)] = make_float2(va, vb);
    }
    __syncthreads();

    // ---- 5 fused radix-2^2 double-stages (s=1..10) ----
#pragma unroll
    for (int sp = 0; sp < 5; ++sp) {
        const int h = 1 << (2 * sp);        // 1,4,16,64,256
#pragma unroll
        for (int it = 0; it < 2; ++it) {    // 512 quads / 256 threads
            const int q    = t + it * 256;
            const int p    = q & (h - 1);
            const int base = ((q >> (2 * sp)) << (2 * sp + 2)) + p;
            const float2 w1 = twg[h + p];           // stage s twiddle
            const float2 w2 = twg[2 * h + p];       // stage s+1 twiddle
            const int ia = pidx(base);
            const int ib = pidx(base + h);
            const int ic = pidx(base + 2 * h);
            const int id = pidx(base + 3 * h);
            const float2 A = z[ia], B = z[ib], C = z[ic], D = z[id];
            // stage s: pairs (A,B) and (C,D), both with w1
            const float2 t1 = cmul(B, w1);
            const float2 t2 = cmul(D, w1);
            const float2 A1 = cadd(A, t1), B1 = csub(A, t1);
            const float2 C1 = cadd(C, t2), D1 = csub(C, t2);
            // stage s+1: pair (A1,C1) with w2; pair (B1,D1) with -i*w2
            const float2 w2m = make_float2(w2.y, -w2.x);   // -i * w2
            const float2 t3 = cmul(C1, w2);
            const float2 t4 = cmul(D1, w2m);
            z[ia] = cadd(A1, t3);
            z[ic] = csub(A1, t3);
            z[ib] = cadd(B1, t4);
            z[id] = csub(B1, t4);
        }
        __syncthreads();
    }

    // ---- final radix-2 stage (s=11, half=1024) ----
#pragma unroll
    for (int it = 0; it < 4; ++it) {
        const int q = t + it * 256;
        const float2 w  = twg[1024 + q];
        const int   ii = pidx(q), jj = pidx(q + 1024);
        const float2 zi = z[ii], zj = z[jj];
        const float2 v  = cmul(zj, w);
        z[ii] = cadd(zi, v);
        z[jj] = csub(zi, v);
    }
    __syncthreads();

    // ---- unpack two real spectra, write interleaved spec2[b][f][k] ----
    const size_t rowa = ((size_t)b * NFRAMES + fa) * NBINS;
    const size_t rowb = ((size_t)b * NFRAMES + fb) * NBINS;
    for (int k = t; k < NBINS; k += 256) {
        const float2 zk = z[pidx(k)];
        const float2 zr = z[pidx((N_FFT - k) & (N_FFT - 1))];
        spec2[rowa + k] = make_float2(0.5f * (zk.x + zr.x), 0.5f * (zk.y - zr.y));
        if (hasb)
            spec2[rowb + k] = make_float2(0.5f * (zk.y + zr.y), 0.5f * (zr.x - zk.x));
    }
}

// spec2 [b][f][k] (float2) -> out real [b][k][f] ++ imag [b][k][f]
// 64x64 tiles: 512 B contiguous reads, 256 B contiguous writes per plane.
__global__ __launch_bounds__(256) void transpose64(
    const float2* __restrict__ spec2,
    float* __restrict__ out)
{
    __shared__ float2 tile[64][65];
    const int kt = blockIdx.x;           // 0..16
    const int ft = blockIdx.y;           // 0..8
    const int b  = blockIdx.z;           // 0..15
    const int k0 = kt * 64, f0 = ft * 64;
    const int tx = threadIdx.x & 63;
    const int ty = threadIdx.x >> 6;     // 0..3

    const float2* in = spec2 + (size_t)b * NFRAMES * NBINS;
#pragma unroll
    for (int i = 0; i < 16; ++i) {
        const int fl = ty + 4 * i;
        const int f  = f0 + fl;
        const int k  = k0 + tx;
        tile[fl][tx] = (f < NFRAMES && k < NBINS)
                     ? in[(size_t)f * NBINS + k] : make_float2(0.0f, 0.0f);
    }
    __syncthreads();

    float* __restrict__ outr = out;
    float* __restrict__ outi = out + HALF_OUT;
#pragma unroll
    for (int i = 0; i < 16; ++i) {
        const int kl = ty + 4 * i;
        const int k  = k0 + kl;
        const int f  = f0 + tx;
        if (k < NBINS && f < NFRAMES) {
            const float2 v = tile[tx][kl];
            const size_t o = ((size_t)b * NBINS + k) * NFRAMES + f;
            outr[o] = v.x;
            outi[o] = v.y;
        }
    }
}

extern "C" void kernel_launch(void* const* d_in, const int* in_sizes, int n_in,
                              void* d_out, int out_size, void* d_ws, size_t ws_size,
                              hipStream_t stream) {
    const float* x      = (const float*)d_in[0];
    const float* window = (const float*)d_in[1];
    float* out          = (float*)d_out;

    float2* tw    = (float2*)d_ws;
    float2* spec2 = tw + TW_COUNT;
    // ws needed: 16 KB + 67.3 MB (same as round 3, which fit)

    twiddle_init<<<8, 256, 0, stream>>>(tw);

    dim3 gfft((NFRAMES + 1) / 2, NBATCH);   // 257 x 16 = 4112 blocks
    stft_fft_r4<<<gfft, 256, 0, stream>>>(x, window, tw, spec2);

    dim3 gt(17, 9, NBATCH);                  // 64x64 tiles over [k=1025][f=513]
    transpose64<<<gt, 256, 0, stream>>>(spec2, out);
}

// Round 6
// 136.266 us; speedup vs baseline: 1.4211x; 1.0038x over previous
//
#include <hip/hip_runtime.h>

// STFT: x[16, 262144] fp32, Hann 2048, hop 512, reflect pad 1024.
// Output: real[16,1025,513] ++ imag[16,1025,513], fp32.
//
// Round 6: ONE kernel, NO workspace (empirically, touching d_ws costs
// ~45-60 us of timed harness poison overhead; R1 no-ws gap was 8 us).
//  - 16 frames/block = 8 packed complex 2048-FFTs, 1024 threads, 152 KB LDS
//    (1 block/CU). Lane writes 64 B contiguous per plane per row -> amp <=1.94x
//    (R4's 32 B spans measured 3.17x).
//  - Swizzle so blocks (g, g+1) of one batch land on the SAME XCD (dispatch
//    ids differing by 8): the boundary sector they share merges in that XCD's
//    L2 -> expected write amp ~1.5x, full-line evictions.
//  - Twiddles from a 4.2 KB padded LDS cos table (cos(pi*j/1024), j=0..1024);
//    w(p,h) = (tab[p*1024/h], -tab[|512 - p*1024/h|]). Padding j+(j>>5) keeps
//    the strided stage-table reads conflict-free.
//  - Grid exactly 512 blocks (32 f-groups x 16 batches): group 31 carries the
//    odd 513th frame as a 9th packed FFT. Two clean 256-block rounds; round-2
//    compute overlaps round-1 write drain.

#define N_FFT   2048
#define LOG2N   11
#define HOP     512
#define PADL    1024
#define NBINS   1025
#define NFRAMES 513
#define NBATCH  16
#define TLEN    262144

#define HALF_OUT ((size_t)NBATCH * NBINS * NFRAMES)   // 8,413,200 floats per plane

__device__ __forceinline__ int pidx(int a) { return a + (a >> 5); }
__device__ __forceinline__ int tix(int j)  { return j + (j >> 5); }

__device__ __forceinline__ int refl(int j) {
    if (j < 0)          j = -j;
    else if (j >= TLEN) j = 2 * TLEN - 2 - j;
    return j;
}

__device__ __forceinline__ float2 cmul(float2 a, float2 w) {
    return make_float2(fmaf(a.x, w.x, -a.y * w.y), fmaf(a.x, w.y, a.y * w.x));
}
__device__ __forceinline__ float2 cadd(float2 a, float2 b) {
    return make_float2(a.x + b.x, a.y + b.y);
}
__device__ __forceinline__ float2 csub(float2 a, float2 b) {
    return make_float2(a.x - b.x, a.y - b.y);
}

__global__ __launch_bounds__(1024) void stft_one(
    const float* __restrict__ x,
    const float* __restrict__ window,
    float* __restrict__ out)
{
    __shared__ float2 z[9][2112];     // 9 packed FFTs, pidx(2047)=2110 -> 152.1 KB
    __shared__ float  tab[1057];      // cos(pi*j/1024), padded, 4.2 KB

    // ---- swizzle: pair blocks (g even, g+1) onto the same XCD (ids differ by 8)
    const int d     = blockIdx.x + 32 * blockIdx.y;   // linear id [0,512)
    const int pair  = (d >> 4) * 8 + (d & 7);         // [0,256)
    const int gg    = 2 * pair + ((d >> 3) & 1);      // [0,512)
    const int b     = gg >> 5;
    const int g     = gg & 31;
    const int tid   = threadIdx.x;
    const int f0    = g * 16;
    const int nsub  = (g == 31) ? 9 : 8;              // group 31 also does frame 512

    // ---- cos table ----
    for (int j = tid; j <= 1024; j += 1024)
        tab[tix(j)] = cosf(3.14159265358979323846f * (float)j * (1.0f / 1024.0f));

    // ---- load nsub*2 windowed frames, bit-reversed ----
    const float* xb = x + (size_t)b * TLEN;
    for (int idx = tid; idx < nsub * 2048; idx += 1024) {
        const int c  = idx >> 11;
        const int n  = idx & 2047;
        const int fa = f0 + 2 * c;                    // frame pair (fa, fa+1)
        const float w  = window[n];
        const float va = xb[refl(fa * HOP - PADL + n)] * w;
        const float vb = xb[refl((fa + 1) * HOP - PADL + n)] * w;  // fa+1=513 phantom ok
        const int r = (int)(__brev((unsigned)n) >> (32 - LOG2N));
        z[c][pidx(r)] = make_float2(va, vb);
    }
    __syncthreads();

    // ---- 5 fused radix-2^2 double-stages (s=1..10) ----
#pragma unroll
    for (int sp = 0; sp < 5; ++sp) {
        const int h = 1 << (2 * sp);                  // 1,4,16,64,256
        for (int idx = tid; idx < nsub * 512; idx += 1024) {
            const int c    = idx >> 9;
            const int q    = idx & 511;
            const int p    = q & (h - 1);
            const int base = ((q >> (2 * sp)) << (2 * sp + 2)) + p;
            const int j1   = p << (10 - 2 * sp);      // stage s twiddle index
            const int j2   = j1 >> 1;                 // stage s+1 twiddle index
            const float2 w1 = make_float2(tab[tix(j1)], -tab[tix(abs(512 - j1))]);
            const float2 w2 = make_float2(tab[tix(j2)], -tab[tix(abs(512 - j2))]);
            const int ia = pidx(base);
            const int ib = pidx(base + h);
            const int ic = pidx(base + 2 * h);
            const int id = pidx(base + 3 * h);
            const float2 A = z[c][ia], B = z[c][ib], C = z[c][ic], D = z[c][id];
            const float2 t1 = cmul(B, w1);
            const float2 t2 = cmul(D, w1);
            const float2 A1 = cadd(A, t1), B1 = csub(A, t1);
            const float2 C1 = cadd(C, t2), D1 = csub(C, t2);
            const float2 w2m = make_float2(w2.y, -w2.x);   // -i * w2
            const float2 t3 = cmul(C1, w2);
            const float2 t4 = cmul(D1, w2m);
            z[c][ia] = cadd(A1, t3);
            z[c][ic] = csub(A1, t3);
            z[c][ib] = cadd(B1, t4);
            z[c][id] = csub(B1, t4);
        }
        __syncthreads();
    }

    // ---- final radix-2 stage (s=11, half=1024) ----
    for (int idx = tid; idx < nsub * 1024; idx += 1024) {
        const int c = idx >> 10;
        const int q = idx & 1023;
        const float2 w = make_float2(tab[tix(q)], -tab[tix(abs(512 - q))]);
        const int ii = pidx(q), jj = pidx(q + 1024);
        const float2 zi = z[c][ii], zj = z[c][jj];
        const float2 v  = cmul(zj, w);
        z[c][ii] = cadd(zi, v);
        z[c][jj] = csub(zi, v);
    }
    __syncthreads();

    // ---- unpack + direct write: out[b][k][f0..f0+15(+1)] ----
    float* __restrict__ outr = out;
    float* __restrict__ outi = out + HALF_OUT;
    for (int k = tid; k < NBINS; k += 1024) {
        const int km = (N_FFT - k) & (N_FFT - 1);
        const size_t orow = ((size_t)b * NBINS + (size_t)k) * NFRAMES + (size_t)f0;
#pragma unroll
        for (int c = 0; c < 8; ++c) {
            const float2 zk = z[c][pidx(k)];
            const float2 zr = z[c][pidx(km)];
            outr[orow + 2 * c]     = 0.5f * (zk.x + zr.x);   // even frame re
            outr[orow + 2 * c + 1] = 0.5f * (zk.y + zr.y);   // odd frame re
            outi[orow + 2 * c]     = 0.5f * (zk.y - zr.y);   // even frame im
            outi[orow + 2 * c + 1] = 0.5f * (zr.x - zk.x);   // odd frame im
        }
        if (nsub == 9) {   // frame 512 (real part of 9th packed FFT)
            const float2 zk = z[8][pidx(k)];
            const float2 zr = z[8][pidx(km)];
            outr[orow + 16] = 0.5f * (zk.x + zr.x);
            outi[orow + 16] = 0.5f * (zk.y - zr.y);
        }
    }
}

extern "C" void kernel_launch(void* const* d_in, const int* in_sizes, int n_in,
                              void* d_out, int out_size, void* d_ws, size_t ws_size,
                              hipStream_t stream) {
    const float* x      = (const float*)d_in[0];
    const float* window = (const float*)d_in[1];
    float* out          = (float*)d_out;

    dim3 grid(32, NBATCH);   // 512 blocks x 1024 threads; d_ws deliberately unused
    stft_one<<<grid, 1024, 0, stream>>>(x, window, out);
}

// Round 7
// 127.697 us; speedup vs baseline: 1.5164x; 1.0671x over previous
//
#include <hip/hip_runtime.h>

// STFT: x[16, 262144] fp32, Hann 2048, hop 512, reflect pad 1024.
// Output: real[16,1025,513] ++ imag[16,1025,513], fp32.
//
// Round 7: same single-kernel/no-ws structure as R6 (passing, 77 us kernel),
// with the FFT core rebuilt to cut LDS issue + barriers (the R6 bottleneck:
// ~350K thread-LDS-ops/block, 8 barriers, 1 block/CU):
//  - 11 stages = 3 radix-8 octet passes (h=1,8,64; 3 stages in registers per
//    LDS round trip) + 1 radix-4 quad pass (h=512). Barriers 7 -> 5,
//    data LDS ops -33%.
//  - Twiddle LDS table removed: w3 = exp(-i*pi*p/(4h)) via __sincosf
//    (v_sin/v_cos, ~1e-6 err << 2.53 threshold); w2 = w3^2, w1 = w2^2 by
//    complex squaring. Removes 92K table reads/block.
//  - Everything else identical to R6: 16 frames/block (8 packed FFTs + 9th on
//    the tail group), 1024 threads, 64 B/plane contiguous writes, XCD-pair
//    swizzle, reflect+window prologue, conjugate-symmetry unpack epilogue.

#define N_FFT   2048
#define LOG2N   11
#define HOP     512
#define PADL    1024
#define NBINS   1025
#define NFRAMES 513
#define NBATCH  16
#define TLEN    262144

#define HALF_OUT ((size_t)NBATCH * NBINS * NFRAMES)   // 8,413,200 floats per plane

__device__ __forceinline__ int pidx(int a) { return a + (a >> 5); }

__device__ __forceinline__ int refl(int j) {
    if (j < 0)          j = -j;
    else if (j >= TLEN) j = 2 * TLEN - 2 - j;
    return j;
}

__device__ __forceinline__ float2 cmul(float2 a, float2 w) {
    return make_float2(fmaf(a.x, w.x, -a.y * w.y), fmaf(a.x, w.y, a.y * w.x));
}
__device__ __forceinline__ float2 cadd(float2 a, float2 b) {
    return make_float2(a.x + b.x, a.y + b.y);
}
__device__ __forceinline__ float2 csub(float2 a, float2 b) {
    return make_float2(a.x - b.x, a.y - b.y);
}
__device__ __forceinline__ float2 csqr(float2 w) {
    return make_float2(fmaf(w.x, w.x, -w.y * w.y), 2.0f * w.x * w.y);
}

// Three DIT stages (halves H, 2H, 4H) on points base + m*H, m=0..7, in registers.
template <int H, int L2H>
__device__ __forceinline__ void octet_pass(float2* __restrict__ zc, int q) {
    const int p    = q & (H - 1);
    const int base = ((q >> L2H) << (L2H + 3)) + p;
    int ia[8];
#pragma unroll
    for (int m = 0; m < 8; ++m) ia[m] = pidx(base + m * H);
    float2 v0 = zc[ia[0]], v1 = zc[ia[1]], v2 = zc[ia[2]], v3 = zc[ia[3]];
    float2 v4 = zc[ia[4]], v5 = zc[ia[5]], v6 = zc[ia[6]], v7 = zc[ia[7]];

    float2 w1, w2, w3;
    if (H == 1) {
        w3 = make_float2(1.0f, 0.0f); w2 = w3; w1 = w3;   // p==0 always
    } else {
        float s, c;
        __sincosf((float)p * (-3.14159265358979323846f / (4.0f * (float)H)), &s, &c);
        w3 = make_float2(c, s);
        w2 = csqr(w3);
        w1 = csqr(w2);
    }

    float2 t;
    // stage A (half=H): pairs (0,1)(2,3)(4,5)(6,7), all twiddle w1
    t = cmul(v1, w1); v1 = csub(v0, t); v0 = cadd(v0, t);
    t = cmul(v3, w1); v3 = csub(v2, t); v2 = cadd(v2, t);
    t = cmul(v5, w1); v5 = csub(v4, t); v4 = cadd(v4, t);
    t = cmul(v7, w1); v7 = csub(v6, t); v6 = cadd(v6, t);
    // stage B (half=2H): pairs (0,2)(4,6) w2 ; (1,3)(5,7) -i*w2
    const float2 w2m = make_float2(w2.y, -w2.x);
    t = cmul(v2, w2);  v2 = csub(v0, t); v0 = cadd(v0, t);
    t = cmul(v3, w2m); v3 = csub(v1, t); v1 = cadd(v1, t);
    t = cmul(v6, w2);  v6 = csub(v4, t); v4 = cadd(v4, t);
    t = cmul(v7, w2m); v7 = csub(v5, t); v5 = cadd(v5, t);
    // stage C (half=4H): pairs (0,4) w3 ; (1,5) w3*e^{-i pi/4} ; (2,6) -i*w3 ; (3,7) -i*w3*e^{-i pi/4}
    const float R = 0.70710678118654752f;
    const float2 w3o  = make_float2((w3.x + w3.y) * R, (w3.y - w3.x) * R);
    const float2 w3m  = make_float2(w3.y, -w3.x);
    const float2 w3mo = make_float2(w3o.y, -w3o.x);
    t = cmul(v4, w3);   v4 = csub(v0, t); v0 = cadd(v0, t);
    t = cmul(v5, w3o);  v5 = csub(v1, t); v1 = cadd(v1, t);
    t = cmul(v6, w3m);  v6 = csub(v2, t); v2 = cadd(v2, t);
    t = cmul(v7, w3mo); v7 = csub(v3, t); v3 = cadd(v3, t);

    zc[ia[0]] = v0; zc[ia[1]] = v1; zc[ia[2]] = v2; zc[ia[3]] = v3;
    zc[ia[4]] = v4; zc[ia[5]] = v5; zc[ia[6]] = v6; zc[ia[7]] = v7;
}

__global__ __launch_bounds__(1024) void stft_one(
    const float* __restrict__ x,
    const float* __restrict__ window,
    float* __restrict__ out)
{
    __shared__ float2 z[9][2112];     // 9 packed FFTs, pidx(2047)=2110 -> 148.5 KB

    // swizzle: pair blocks (g even, g+1) onto the same XCD (ids differ by 8)
    const int d     = blockIdx.x + 32 * blockIdx.y;   // [0,512)
    const int pair  = (d >> 4) * 8 + (d & 7);         // [0,256)
    const int gg    = 2 * pair + ((d >> 3) & 1);      // [0,512)
    const int b     = gg >> 5;
    const int g     = gg & 31;
    const int tid   = threadIdx.x;
    const int f0    = g * 16;
    const int nsub  = (g == 31) ? 9 : 8;              // tail group also does frame 512

    // ---- load nsub*2 windowed frames, bit-reversed ----
    const float* xb = x + (size_t)b * TLEN;
    for (int idx = tid; idx < nsub * 2048; idx += 1024) {
        const int c  = idx >> 11;
        const int n  = idx & 2047;
        const int fa = f0 + 2 * c;
        const float w  = window[n];
        const float va = xb[refl(fa * HOP - PADL + n)] * w;
        const float vb = xb[refl((fa + 1) * HOP - PADL + n)] * w;  // phantom frame ok
        const int r = (int)(__brev((unsigned)n) >> (32 - LOG2N));
        z[c][pidx(r)] = make_float2(va, vb);
    }
    __syncthreads();

    // ---- stages 1-3 (h=1), 4-6 (h=8), 7-9 (h=64): radix-8 register passes ----
    for (int idx = tid; idx < nsub * 256; idx += 1024)
        octet_pass<1, 0>(z[idx >> 8], idx & 255);
    __syncthreads();
    for (int idx = tid; idx < nsub * 256; idx += 1024)
        octet_pass<8, 3>(z[idx >> 8], idx & 255);
    __syncthreads();
    for (int idx = tid; idx < nsub * 256; idx += 1024)
        octet_pass<64, 6>(z[idx >> 8], idx & 255);
    __syncthreads();

    // ---- stages 10-11: radix-4 quad pass (h=512) ----
    for (int idx = tid; idx < nsub * 512; idx += 1024) {
        const int c = idx >> 9;
        const int p = idx & 511;
        float s, cc;
        __sincosf((float)p * (-3.14159265358979323846f / 1024.0f), &s, &cc);
        const float2 w2  = make_float2(cc, s);        // exp(-i*pi*p/1024)
        const float2 w1  = csqr(w2);                  // exp(-i*pi*p/512)
        const float2 w2m = make_float2(w2.y, -w2.x);  // -i*w2
        const int i0 = pidx(p), i1 = pidx(p + 512), i2 = pidx(p + 1024), i3 = pidx(p + 1536);
        float2 v0 = z[c][i0], v1 = z[c][i1], v2 = z[c][i2], v3 = z[c][i3];
        float2 t;
        // half=512: pairs (0,1)(2,3), twiddle w1
        t = cmul(v1, w1); v1 = csub(v0, t); v0 = cadd(v0, t);
        t = cmul(v3, w1); v3 = csub(v2, t); v2 = cadd(v2, t);
        // half=1024: pair (0,2) w2 ; pair (1,3) -i*w2
        t = cmul(v2, w2);  v2 = csub(v0, t); v0 = cadd(v0, t);
        t = cmul(v3, w2m); v3 = csub(v1, t); v1 = cadd(v1, t);
        z[c][i0] = v0; z[c][i1] = v1; z[c][i2] = v2; z[c][i3] = v3;
    }
    __syncthreads();

    // ---- unpack + direct write: out[b][k][f0..f0+15(+1)] ----
    float* __restrict__ outr = out;
    float* __restrict__ outi = out + HALF_OUT;
    for (int k = tid; k < NBINS; k += 1024) {
        const int km = (N_FFT - k) & (N_FFT - 1);
        const size_t orow = ((size_t)b * NBINS + (size_t)k) * NFRAMES + (size_t)f0;
#pragma unroll
        for (int c = 0; c < 8; ++c) {
            const float2 zk = z[c][pidx(k)];
            const float2 zr = z[c][pidx(km)];
            outr[orow + 2 * c]     = 0.5f * (zk.x + zr.x);   // even frame re
            outr[orow + 2 * c + 1] = 0.5f * (zk.y + zr.y);   // odd frame re
            outi[orow + 2 * c]     = 0.5f * (zk.y - zr.y);   // even frame im
            outi[orow + 2 * c + 1] = 0.5f * (zr.x - zk.x);   // odd frame im
        }
        if (nsub == 9) {   // frame 512 (real part of 9th packed FFT)
            const float2 zk = z[8][pidx(k)];
            const float2 zr = z[8][pidx(km)];
            outr[orow + 16] = 0.5f * (zk.x + zr.x);
            outi[orow + 16] = 0.5f * (zk.y - zr.y);
        }
    }
}

extern "C" void kernel_launch(void* const* d_in, const int* in_sizes, int n_in,
                              void* d_out, int out_size, void* d_ws, size_t ws_size,
                              hipStream_t stream) {
    const float* x      = (const float*)d_in[0];
    const float* window = (const float*)d_in[1];
    float* out          = (float*)d_out;

    dim3 grid(32, NBATCH);   // 512 blocks x 1024 threads; d_ws deliberately unused
    stft_one<<<grid, 1024, 0, stream>>>(x, window, out);
}